// Round 5
// baseline (195.688 us; speedup 1.0000x reference)
//
#include <hip/hip_runtime.h>
#include <math.h>
#include <stdint.h>

#define BN 2048
#define KF 512
#define OF 512
#define NH 8
#define DD 64
#define NBLK 512
#define JT 64
#define NC (BN / JT)

typedef __attribute__((ext_vector_type(8))) short short8;
typedef __attribute__((ext_vector_type(4))) float f32x4;
typedef unsigned short ushortT;

static __device__ __forceinline__ ushortT f2bf(float f) {
  unsigned u = __float_as_uint(f);
  u += 0x7fffu + ((u >> 16) & 1u);   // RNE
  return (ushortT)(u >> 16);
}
static __device__ __forceinline__ float bf2f(ushortT b) {
  return __uint_as_float(((unsigned)b) << 16);
}

// ---- contention-free barrier primitives ----
// arrival: release-store to a per-block slot (distinct lines of traffic, no RMW)
static __device__ __forceinline__ void bar_arrive(unsigned* arr, int b, unsigned v) {
  __threadfence();   // prior global writes visible before arrival
  __hip_atomic_store(arr + b, v, __ATOMIC_RELEASE, __HIP_MEMORY_SCOPE_AGENT);
}
static __device__ __forceinline__ void bar_waitflag(const unsigned* f, unsigned v) {
  while (__hip_atomic_load(f, __ATOMIC_ACQUIRE, __HIP_MEMORY_SCOPE_AGENT) < v)
    __builtin_amdgcn_s_sleep(16);
}

__global__ __launch_bounds__(256, 2) void k_mega(
    const float* __restrict__ x, const int* __restrict__ adj,
    const float* __restrict__ W, const float* __restrict__ Wb,
    const float* __restrict__ av,
    ushortT* __restrict__ hbT, float* __restrict__ E12d,
    ushortT* __restrict__ wh, ushortT* __restrict__ wl,
    uint8_t* __restrict__ adjB, unsigned* __restrict__ bbar,
    float* __restrict__ out) {
  __shared__ __align__(16) uint8_t smem[49664];
  __shared__ float e12s_loc[32][2];
  __shared__ float sredS[2][32], sredD[2][32];
  __shared__ float denl[32];

  const int t    = threadIdx.x;
  const int b    = blockIdx.x;
  const int hh   = b >> 6;
  const int i0   = (b & 63) * 32;
  const int lane = t & 63;
  const int wv   = t >> 6;
  const int mt   = wv & 1;
  const int nt   = wv >> 1;
  const int l15  = lane & 15;
  const int lq   = lane >> 4;

  unsigned* arr   = bbar;              // [512] arrival slots
  unsigned* gflag = bbar + 512;        // grid release flag (padded line)
  unsigned* hflag = bbar + 544;        // [8][32] per-head flags, 128B apart

  // ================= Phase A: W hi/lo split + adj bitpack =================
  {
    const int gtid = b * 256 + t;
    if (gtid < (OF * KF / 8)) {
      const float* src = W + (size_t)gtid * 8;
      float v[8];
      *(float4*)&v[0] = *(const float4*)src;
      *(float4*)&v[4] = *(const float4*)(src + 4);
      ushortT hi8[8], lo8[8];
#pragma unroll
      for (int i = 0; i < 8; ++i) {
        hi8[i] = f2bf(v[i]);
        lo8[i] = f2bf(v[i] - bf2f(hi8[i]));
      }
      *(int4*)(wh + (size_t)gtid * 8) = *(const int4*)hi8;
      *(int4*)(wl + (size_t)gtid * 8) = *(const int4*)lo8;
    }
#pragma unroll
    for (int it = 0; it < 4; ++it) {
      const int bidx = gtid + it * (NBLK * 256);
      const int4 v0 = *(const int4*)(adj + (size_t)bidx * 8);
      const int4 v1 = *(const int4*)(adj + (size_t)bidx * 8 + 4);
      unsigned m = (v0.x ? 1u : 0u) | (v0.y ? 2u : 0u) | (v0.z ? 4u : 0u) | (v0.w ? 8u : 0u)
                 | (v1.x ? 16u : 0u) | (v1.y ? 32u : 0u) | (v1.z ? 64u : 0u) | (v1.w ? 128u : 0u);
      adjB[bidx] = (uint8_t)m;
    }
  }

  // ---- grid barrier (flag-array, no contended RMW) ----
  __syncthreads();
  if (b == 0) {
    if (t == 0) bar_arrive(arr, 0, 1u);
    if (t < 64) {
      bool done = false;
      while (!done) {
        int ok = 1;
#pragma unroll
        for (int k = 0; k < 8; ++k)
          ok &= (__hip_atomic_load(arr + t * 8 + k, __ATOMIC_ACQUIRE,
                                   __HIP_MEMORY_SCOPE_AGENT) >= 1u);
        done = __all(ok);
        if (!done) __builtin_amdgcn_s_sleep(8);
      }
      if (t == 0) {
        __threadfence();
        __hip_atomic_store(gflag, 1u, __ATOMIC_RELEASE, __HIP_MEMORY_SCOPE_AGENT);
      }
    }
  } else {
    if (t == 0) {
      bar_arrive(arr, b, 1u);
      bar_waitflag(gflag, 1u);
    }
  }
  __syncthreads();

  // ================= Phase B: GEMM (32i x 64f tile) + scores ==============
  {
    ushortT* sAh = (ushortT*)smem;
    ushortT* sAl = sAh + 32 * 64;
    ushortT* sBh = sAl + 32 * 64;
    ushortT* sBl = sBh + 64 * 64;

    f32x4 acc[2] = {};
    const int srow = t >> 3, ss = t & 7;
    int4 aHi, aLo, bHi[2], bLo[2];

    {
      const float* xs = x + (size_t)(i0 + srow) * KF + ss * 8;
      float v[8];
      *(float4*)&v[0] = *(const float4*)xs;
      *(float4*)&v[4] = *(const float4*)(xs + 4);
      ushortT hi8[8], lo8[8];
#pragma unroll
      for (int i = 0; i < 8; ++i) { hi8[i] = f2bf(v[i]); lo8[i] = f2bf(v[i] - bf2f(hi8[i])); }
      aHi = *(const int4*)hi8; aLo = *(const int4*)lo8;
#pragma unroll
      for (int rep = 0; rep < 2; ++rep) {
        const int S = t + rep * 256, rw = S >> 3, s2 = S & 7;
        const size_t gb = (size_t)(hh * 64 + rw) * KF + s2 * 8;
        bHi[rep] = *(const int4*)(wh + gb);
        bLo[rep] = *(const int4*)(wl + gb);
      }
    }

    for (int k0 = 0; k0 < 8; ++k0) {
      __syncthreads();
      {
        const int offA = srow * 64 + ((ss ^ (srow & 7)) * 8);
        *(int4*)&sAh[offA] = aHi;
        *(int4*)&sAl[offA] = aLo;
#pragma unroll
        for (int rep = 0; rep < 2; ++rep) {
          const int S = t + rep * 256, rw = S >> 3, s2 = S & 7;
          const int offB = rw * 64 + ((s2 ^ (rw & 7)) * 8);
          *(int4*)&sBh[offB] = bHi[rep];
          *(int4*)&sBl[offB] = bLo[rep];
        }
      }
      __syncthreads();
      if (k0 < 7) {
        const int kc = (k0 + 1) * 64;
        const float* xs = x + (size_t)(i0 + srow) * KF + kc + ss * 8;
        float v[8];
        *(float4*)&v[0] = *(const float4*)xs;
        *(float4*)&v[4] = *(const float4*)(xs + 4);
        ushortT hi8[8], lo8[8];
#pragma unroll
        for (int i = 0; i < 8; ++i) { hi8[i] = f2bf(v[i]); lo8[i] = f2bf(v[i] - bf2f(hi8[i])); }
        aHi = *(const int4*)hi8; aLo = *(const int4*)lo8;
#pragma unroll
        for (int rep = 0; rep < 2; ++rep) {
          const int S = t + rep * 256, rw = S >> 3, s2 = S & 7;
          const size_t gb = (size_t)(hh * 64 + rw) * KF + kc + s2 * 8;
          bHi[rep] = *(const int4*)(wh + gb);
          bLo[rep] = *(const int4*)(wl + gb);
        }
      }
#pragma unroll
      for (int kb = 0; kb < 2; ++kb) {
        const int sc = kb * 4 + lq;
        const int arow = mt * 16 + l15;
        const int offA = arow * 64 + ((sc ^ (arow & 7)) * 8);
        const short8 afh = *(const short8*)&sAh[offA];
        const short8 afl = *(const short8*)&sAl[offA];
        const int br0 = nt * 32 + l15;
        const int br1 = br0 + 16;
        const int offB0 = br0 * 64 + ((sc ^ (br0 & 7)) * 8);
        const int offB1 = br1 * 64 + ((sc ^ (br1 & 7)) * 8);
        const short8 bh0 = *(const short8*)&sBh[offB0];
        const short8 bl0 = *(const short8*)&sBl[offB0];
        const short8 bh1 = *(const short8*)&sBh[offB1];
        const short8 bl1 = *(const short8*)&sBl[offB1];
        acc[0] = __builtin_amdgcn_mfma_f32_16x16x32_bf16(afh, bh0, acc[0], 0, 0, 0);
        acc[1] = __builtin_amdgcn_mfma_f32_16x16x32_bf16(afh, bh1, acc[1], 0, 0, 0);
        acc[0] = __builtin_amdgcn_mfma_f32_16x16x32_bf16(afh, bl0, acc[0], 0, 0, 0);
        acc[1] = __builtin_amdgcn_mfma_f32_16x16x32_bf16(afh, bl1, acc[1], 0, 0, 0);
        acc[0] = __builtin_amdgcn_mfma_f32_16x16x32_bf16(afl, bh0, acc[0], 0, 0, 0);
        acc[1] = __builtin_amdgcn_mfma_f32_16x16x32_bf16(afl, bh1, acc[1], 0, 0, 0);
      }
    }

    __syncthreads();
    ushortT* ldsT = (ushortT*)smem;   // [64 f][40]
    float bias2[2], asv[2], adv[2];
#pragma unroll
    for (int bb = 0; bb < 2; ++bb) {
      const int fl = nt * 32 + bb * 16 + l15;
      bias2[bb] = Wb[hh * 64 + fl];
      asv[bb] = av[fl];
      adv[bb] = av[DD + fl];
    }
#pragma unroll
    for (int p = 0; p < 4; ++p) {
      float vs = 0.f, vd = 0.f;
#pragma unroll
      for (int bb = 0; bb < 2; ++bb) {
        const float hv = acc[bb][p] + bias2[bb];
        const ushortT hu = f2bf(hv);
        vs = fmaf(hv, asv[bb], vs);
        vd = fmaf(hv, adv[bb], vd);
        ldsT[(nt * 32 + bb * 16 + l15) * 40 + mt * 16 + lq * 4 + p] = hu;
      }
      vs += __shfl_xor(vs, 1); vs += __shfl_xor(vs, 2);
      vs += __shfl_xor(vs, 4); vs += __shfl_xor(vs, 8);
      vd += __shfl_xor(vd, 1); vd += __shfl_xor(vd, 2);
      vd += __shfl_xor(vd, 4); vd += __shfl_xor(vd, 8);
      if (l15 == 0) {
        sredS[nt][mt * 16 + lq * 4 + p] = vs;
        sredD[nt][mt * 16 + lq * 4 + p] = vd;
      }
    }
    __syncthreads();
    if (t < 32) {
      const float s1 = sredS[0][t] + sredS[1][t];
      const float s2 = sredD[0][t] + sredD[1][t];
      e12s_loc[t][0] = __expf(s1);
      e12s_loc[t][1] = __expf(0.2f * s1);
      float2 dv;
      dv.x = __expf(s2);
      dv.y = __expf(0.2f * s2);
      *(float2*)&E12d[((size_t)hh * BN + i0 + t) * 2] = dv;
    }
    {
      const int f = t >> 2, ic = (t & 3) * 8;
      const int4 v = *(const int4*)&ldsT[f * 40 + ic];
      *(int4*)&hbT[(size_t)(hh * 64 + f) * BN + i0 + ic] = v;
    }
  }

  // ---- per-head group barrier (64 blocks) ----
  __syncthreads();
  {
    unsigned* hf = hflag + hh * 32;
    if ((b & 63) == 0) {
      if (t == 0) bar_arrive(arr, b, 2u);
      if (t < 64) {
        bool done = false;
        while (!done) {
          done = __all(__hip_atomic_load(arr + hh * 64 + t, __ATOMIC_ACQUIRE,
                                         __HIP_MEMORY_SCOPE_AGENT) >= 2u);
          if (!done) __builtin_amdgcn_s_sleep(8);
        }
        if (t == 0) {
          __threadfence();
          __hip_atomic_store(hf, 1u, __ATOMIC_RELEASE, __HIP_MEMORY_SCOPE_AGENT);
        }
      }
    } else {
      if (t == 0) {
        bar_arrive(arr, b, 2u);
        bar_waitflag(hf, 1u);
      }
    }
  }
  __syncthreads();

  // ================= Phase C: mask/weight/PV(MFMA)/normalize/ELU ==========
  {
    ushortT* hB0 = (ushortT*)smem;
    ushortT* hB1 = hB0 + 4096;
    ushortT* wA0 = hB1 + 4096;
    ushortT* wA1 = wA0 + 2048;
    float* e12 = (float*)(wA1 + 2048);
    uint8_t* abits = (uint8_t*)(e12 + 4096);

    {
      const float4* g = (const float4*)(E12d + (size_t)hh * BN * 2);
#pragma unroll
      for (int rep = 0; rep < 4; ++rep) {
        const int Q = t + rep * 256;
        const int q = Q & 31;
        const int slot = (Q & ~31) + (q & 3) * 8 + (q >> 2);
        ((float4*)e12)[slot] = g[Q];
      }
      const int r = t >> 3, p = t & 7;
      const int4* ga = (const int4*)(adjB + (size_t)(i0 + r) * 256 + p * 32);
      const int4 b0 = ga[0], b1 = ga[1];
      *(int4*)(abits + r * 272 + p * 32) = b0;
      *(int4*)(abits + r * 272 + p * 32 + 16) = b1;
    }

    const int wi = t >> 3, jg = t & 7;
    const float e1i = e12s_loc[wi][0];
    const float e2i = e12s_loc[wi][1];
    float denp = 0.f;

    const int nt0 = (wv >> 1) * 2;
    const int arow = mt * 16 + l15;
    const int bn0 = nt0 * 16 + l15;
    f32x4 acc0 = {0.f, 0.f, 0.f, 0.f}, acc1 = {0.f, 0.f, 0.f, 0.f};

    const int S0 = t, S1 = t + 256;
    const size_t gh0 = (size_t)(hh * 64 + (S0 >> 3)) * BN + (S0 & 7) * 8;
    const size_t gh1 = (size_t)(hh * 64 + (S1 >> 3)) * BN + (S1 & 7) * 8;
    const int lo0 = (S0 >> 3) * 64 + (((S0 & 7) ^ ((S0 >> 3) & 7)) * 8);
    const int lo1 = (S1 >> 3) * 64 + (((S1 & 7) ^ ((S1 >> 3) & 7)) * 8);
    const int loW = wi * 64 + ((jg ^ (wi & 7)) * 8);

#define COMPUTE_W(cc, wbv)                                                    \
  {                                                                           \
    const uint64_t bits64 = *(const uint64_t*)(abits + wi * 272 + (cc) * 8);  \
    const unsigned bbyte = (unsigned)(bits64 >> (jg * 8)) & 0xffu;            \
    const float4* eb = ((const float4*)e12) + (cc) * 32 + jg;                 \
    const float4 r0 = eb[0];                                                  \
    const float4 r1 = eb[8];                                                  \
    const float4 r2 = eb[16];                                                 \
    const float4 r3 = eb[24];                                                 \
    float d1[8], d2[8];                                                       \
    d1[0] = r0.x; d2[0] = r0.y; d1[1] = r0.z; d2[1] = r0.w;                   \
    d1[2] = r1.x; d2[2] = r1.y; d1[3] = r1.z; d2[3] = r1.w;                   \
    d1[4] = r2.x; d2[4] = r2.y; d1[5] = r2.z; d2[5] = r2.w;                   \
    d1[6] = r3.x; d2[6] = r3.y; d1[7] = r3.z; d2[7] = r3.w;                   \
    _Pragma("unroll")                                                         \
    for (int e = 0; e < 8; ++e) {                                             \
      const float p1 = e1i * d1[e];                                           \
      const float p2 = e2i * d2[e];                                           \
      float w = fmaxf(p1, p2);                                                \
      w = ((bbyte >> e) & 1u) ? w : 0.f;                                      \
      const ushortT wu = f2bf(w);                                             \
      (wbv)[e] = (short)wu;                                                   \
      denp += bf2f(wu);                                                       \
    }                                                                         \
  }

    int4 hv0 = *(const int4*)(hbT + gh0);
    int4 hv1 = *(const int4*)(hbT + gh1);
    __syncthreads();
    {
      short8 wb;
      COMPUTE_W(0, wb)
      *(int4*)&hB0[lo0] = hv0;
      *(int4*)&hB0[lo1] = hv1;
      *(short8*)&wA0[loW] = wb;
    }
    __syncthreads();

    for (int c = 0; c < NC; ++c) {
      const ushortT* hBc = (c & 1) ? hB1 : hB0;
      const ushortT* wAc = (c & 1) ? wA1 : wA0;
      short8 wb;
      if (c < NC - 1) {
        const size_t joff = (size_t)(c + 1) * JT;
        hv0 = *(const int4*)(hbT + gh0 + joff);
        hv1 = *(const int4*)(hbT + gh1 + joff);
        COMPUTE_W(c + 1, wb)
      }
#pragma unroll
      for (int kb = 0; kb < 2; ++kb) {
        const int ks = kb * 4 + lq;
        const short8 af  = *(const short8*)(wAc + arow * 64 + ((ks ^ (arow & 7)) * 8));
        const short8 bv0 = *(const short8*)(hBc + bn0 * 64 + ((ks ^ (bn0 & 7)) * 8));
        const short8 bv1 = *(const short8*)(hBc + (bn0 + 16) * 64 + ((ks ^ ((bn0 + 16) & 7)) * 8));
        acc0 = __builtin_amdgcn_mfma_f32_16x16x32_bf16(af, bv0, acc0, 0, 0, 0);
        acc1 = __builtin_amdgcn_mfma_f32_16x16x32_bf16(af, bv1, acc1, 0, 0, 0);
      }
      if (c < NC - 1) {
        ushortT* hBn = (c & 1) ? hB0 : hB1;
        ushortT* wAn = (c & 1) ? wA0 : wA1;
        *(int4*)&hBn[lo0] = hv0;
        *(int4*)&hBn[lo1] = hv1;
        *(short8*)&wAn[loW] = wb;
      }
      __syncthreads();
    }

    {
      float d = denp;
      d += __shfl_xor(d, 1);
      d += __shfl_xor(d, 2);
      d += __shfl_xor(d, 4);
      if ((t & 7) == 0) denl[wi] = d;
    }
    __syncthreads();

#pragma unroll
    for (int q = 0; q < 4; ++q) {
      const int row = mt * 16 + lq * 4 + q;
      const float rd = 1.f / denl[row];
      float v0 = acc0[q] * rd;
      float v1 = acc1[q] * rd;
      v0 = v0 > 0.f ? v0 : expm1f(v0);
      v1 = v1 > 0.f ? v1 : expm1f(v1);
      out[(size_t)(i0 + row) * OF + hh * 64 + nt0 * 16 + l15]       = v0;
      out[(size_t)(i0 + row) * OF + hh * 64 + (nt0 + 1) * 16 + l15] = v1;
    }
#undef COMPUTE_W
  }
}

extern "C" void kernel_launch(void* const* d_in, const int* in_sizes, int n_in,
                              void* d_out, int out_size, void* d_ws, size_t ws_size,
                              hipStream_t stream) {
  const float* x  = (const float*)d_in[0];
  const int* adj  = (const int*)d_in[1];
  const float* Ww = (const float*)d_in[2];
  const float* Wb = (const float*)d_in[3];
  const float* a  = (const float*)d_in[4];
  float* outp = (float*)d_out;

  uint8_t* p = (uint8_t*)d_ws;
  ushortT* hbT  = (ushortT*)(p + 0x000000);   // 2 MB
  float*   E12d = (float*)  (p + 0x200000);   // 128 KB
  ushortT* wh   = (ushortT*)(p + 0x220000);   // 512 KB
  ushortT* wl   = (ushortT*)(p + 0x2A0000);   // 512 KB
  uint8_t* adjB =            p + 0x320000;    // 512 KB
  unsigned* bbar = (unsigned*)(p + 0x3A0000); // barrier state (arr[512]|gflag|hflag)

  hipMemsetAsync(bbar, 0, 4096, stream);
  k_mega<<<dim3(NBLK), dim3(256), 0, stream>>>(x, adj, Ww, Wb, a, hbT, E12d,
                                               wh, wl, adjB, bbar, outp);
}

// Round 6
// 41.251 us; speedup vs baseline: 4.7438x; 4.7438x over previous
//
#include <hip/hip_runtime.h>
#include <math.h>
#include <stdint.h>

#define BN 2048
#define KF 512
#define OF 512
#define NH 8
#define DD 64
#define JT 64
#define NC (BN / JT)

typedef __attribute__((ext_vector_type(8))) short short8;
typedef __attribute__((ext_vector_type(4))) float f32x4;
typedef unsigned short ushortT;

static __device__ __forceinline__ ushortT f2bf(float f) {
  unsigned u = __float_as_uint(f);
  u += 0x7fffu + ((u >> 16) & 1u);   // RNE
  return (ushortT)(u >> 16);
}
static __device__ __forceinline__ float bf2f(ushortT b) {
  return __uint_as_float(((unsigned)b) << 16);
}

// ============ Kernel A: adj bitpack + MFMA split-bf16 GEMM + score tables ====
// grid (NH, BN/32) = 512 blocks, 256 threads.
__global__ __launch_bounds__(256, 2) void k_main(
    const float* __restrict__ x, const int* __restrict__ adj,
    const float* __restrict__ W, const float* __restrict__ Wb,
    const float* __restrict__ av,
    ushortT* __restrict__ hbT, float* __restrict__ E12s, float* __restrict__ E12d,
    uint8_t* __restrict__ adjB) {
  __shared__ __align__(16) uint8_t smem[24576];   // sAh|sAl|sBh|sBl; ldsT overlay
  __shared__ float sredS[2][32], sredD[2][32];

  const int t    = threadIdx.x;
  const int hh   = blockIdx.x;
  const int i0   = blockIdx.y * 32;
  const int b    = hh * 64 + blockIdx.y;
  const int lane = t & 63;
  const int wv   = t >> 6;
  const int mt   = wv & 1;
  const int nt   = wv >> 1;
  const int l15  = lane & 15;
  const int lq   = lane >> 4;

  // ---- prologue: adj bitpack (independent of GEMM; no sync needed) ----
  {
    const int gtid = b * 256 + t;
#pragma unroll
    for (int it = 0; it < 4; ++it) {
      const int bidx = gtid + it * (512 * 256);
      const int4 v0 = *(const int4*)(adj + (size_t)bidx * 8);
      const int4 v1 = *(const int4*)(adj + (size_t)bidx * 8 + 4);
      unsigned m = (v0.x ? 1u : 0u) | (v0.y ? 2u : 0u) | (v0.z ? 4u : 0u) | (v0.w ? 8u : 0u)
                 | (v1.x ? 16u : 0u) | (v1.y ? 32u : 0u) | (v1.z ? 64u : 0u) | (v1.w ? 128u : 0u);
      adjB[bidx] = (uint8_t)m;
    }
  }

  // ---- GEMM: 32i x 64f tile, split-bf16, both operands split in-register ----
  ushortT* sAh = (ushortT*)smem;
  ushortT* sAl = sAh + 32 * 64;
  ushortT* sBh = sAl + 32 * 64;
  ushortT* sBl = sBh + 64 * 64;

  f32x4 acc[2] = {};
  const int srow = t >> 3, ss = t & 7;
  int4 aHi, aLo, bHi[2], bLo[2];

  {  // k0 = 0 loads (fp32 -> hi/lo bf16 in-register)
    const float* xs = x + (size_t)(i0 + srow) * KF + ss * 8;
    float v[8];
    *(float4*)&v[0] = *(const float4*)xs;
    *(float4*)&v[4] = *(const float4*)(xs + 4);
    ushortT hi8[8], lo8[8];
#pragma unroll
    for (int i = 0; i < 8; ++i) { hi8[i] = f2bf(v[i]); lo8[i] = f2bf(v[i] - bf2f(hi8[i])); }
    aHi = *(const int4*)hi8; aLo = *(const int4*)lo8;
#pragma unroll
    for (int rep = 0; rep < 2; ++rep) {
      const int S = t + rep * 256, rw = S >> 3, s2 = S & 7;
      const float* wsrc = W + (size_t)(hh * 64 + rw) * KF + s2 * 8;
      float wv8[8];
      *(float4*)&wv8[0] = *(const float4*)wsrc;
      *(float4*)&wv8[4] = *(const float4*)(wsrc + 4);
      ushortT wh8[8], wl8[8];
#pragma unroll
      for (int i = 0; i < 8; ++i) { wh8[i] = f2bf(wv8[i]); wl8[i] = f2bf(wv8[i] - bf2f(wh8[i])); }
      bHi[rep] = *(const int4*)wh8; bLo[rep] = *(const int4*)wl8;
    }
  }

  for (int k0 = 0; k0 < 8; ++k0) {
    __syncthreads();
    {
      const int offA = srow * 64 + ((ss ^ (srow & 7)) * 8);
      *(int4*)&sAh[offA] = aHi;
      *(int4*)&sAl[offA] = aLo;
#pragma unroll
      for (int rep = 0; rep < 2; ++rep) {
        const int S = t + rep * 256, rw = S >> 3, s2 = S & 7;
        const int offB = rw * 64 + ((s2 ^ (rw & 7)) * 8);
        *(int4*)&sBh[offB] = bHi[rep];
        *(int4*)&sBl[offB] = bLo[rep];
      }
    }
    __syncthreads();
    if (k0 < 7) {
      const int kc = (k0 + 1) * 64;
      const float* xs = x + (size_t)(i0 + srow) * KF + kc + ss * 8;
      float v[8];
      *(float4*)&v[0] = *(const float4*)xs;
      *(float4*)&v[4] = *(const float4*)(xs + 4);
      ushortT hi8[8], lo8[8];
#pragma unroll
      for (int i = 0; i < 8; ++i) { hi8[i] = f2bf(v[i]); lo8[i] = f2bf(v[i] - bf2f(hi8[i])); }
      aHi = *(const int4*)hi8; aLo = *(const int4*)lo8;
#pragma unroll
      for (int rep = 0; rep < 2; ++rep) {
        const int S = t + rep * 256, rw = S >> 3, s2 = S & 7;
        const float* wsrc = W + (size_t)(hh * 64 + rw) * KF + kc + s2 * 8;
        float wv8[8];
        *(float4*)&wv8[0] = *(const float4*)wsrc;
        *(float4*)&wv8[4] = *(const float4*)(wsrc + 4);
        ushortT wh8[8], wl8[8];
#pragma unroll
        for (int i = 0; i < 8; ++i) { wh8[i] = f2bf(wv8[i]); wl8[i] = f2bf(wv8[i] - bf2f(wh8[i])); }
        bHi[rep] = *(const int4*)wh8; bLo[rep] = *(const int4*)wl8;
      }
    }
#pragma unroll
    for (int kb = 0; kb < 2; ++kb) {
      const int sc = kb * 4 + lq;
      const int arow = mt * 16 + l15;
      const int offA = arow * 64 + ((sc ^ (arow & 7)) * 8);
      const short8 afh = *(const short8*)&sAh[offA];
      const short8 afl = *(const short8*)&sAl[offA];
      const int br0 = nt * 32 + l15;
      const int br1 = br0 + 16;
      const int offB0 = br0 * 64 + ((sc ^ (br0 & 7)) * 8);
      const int offB1 = br1 * 64 + ((sc ^ (br1 & 7)) * 8);
      const short8 bh0 = *(const short8*)&sBh[offB0];
      const short8 bl0 = *(const short8*)&sBl[offB0];
      const short8 bh1 = *(const short8*)&sBh[offB1];
      const short8 bl1 = *(const short8*)&sBl[offB1];
      acc[0] = __builtin_amdgcn_mfma_f32_16x16x32_bf16(afh, bh0, acc[0], 0, 0, 0);
      acc[1] = __builtin_amdgcn_mfma_f32_16x16x32_bf16(afh, bh1, acc[1], 0, 0, 0);
      acc[0] = __builtin_amdgcn_mfma_f32_16x16x32_bf16(afh, bl0, acc[0], 0, 0, 0);
      acc[1] = __builtin_amdgcn_mfma_f32_16x16x32_bf16(afh, bl1, acc[1], 0, 0, 0);
      acc[0] = __builtin_amdgcn_mfma_f32_16x16x32_bf16(afl, bh0, acc[0], 0, 0, 0);
      acc[1] = __builtin_amdgcn_mfma_f32_16x16x32_bf16(afl, bh1, acc[1], 0, 0, 0);
    }
  }

  // ---- epilogue: bias, scores, E tables, transposed bf16 h store ----
  __syncthreads();
  ushortT* ldsT = (ushortT*)smem;   // [64 f][40]
  float bias2[2], asv[2], adv[2];
#pragma unroll
  for (int bb = 0; bb < 2; ++bb) {
    const int fl = nt * 32 + bb * 16 + l15;
    bias2[bb] = Wb[hh * 64 + fl];
    asv[bb] = av[fl];
    adv[bb] = av[DD + fl];
  }
#pragma unroll
  for (int p = 0; p < 4; ++p) {
    float vs = 0.f, vd = 0.f;
#pragma unroll
    for (int bb = 0; bb < 2; ++bb) {
      const float hv = acc[bb][p] + bias2[bb];
      const ushortT hu = f2bf(hv);
      vs = fmaf(hv, asv[bb], vs);
      vd = fmaf(hv, adv[bb], vd);
      ldsT[(nt * 32 + bb * 16 + l15) * 40 + mt * 16 + lq * 4 + p] = hu;
    }
    vs += __shfl_xor(vs, 1); vs += __shfl_xor(vs, 2);
    vs += __shfl_xor(vs, 4); vs += __shfl_xor(vs, 8);
    vd += __shfl_xor(vd, 1); vd += __shfl_xor(vd, 2);
    vd += __shfl_xor(vd, 4); vd += __shfl_xor(vd, 8);
    if (l15 == 0) {
      sredS[nt][mt * 16 + lq * 4 + p] = vs;
      sredD[nt][mt * 16 + lq * 4 + p] = vd;
    }
  }
  __syncthreads();
  if (t < 32) {
    const float s1 = sredS[0][t] + sredS[1][t];
    const float s2 = sredD[0][t] + sredD[1][t];
    const size_t gi = (size_t)hh * BN + i0 + t;
    float2 sv; sv.x = __expf(s1); sv.y = __expf(0.2f * s1);
    float2 dv; dv.x = __expf(s2); dv.y = __expf(0.2f * s2);
    *(float2*)&E12s[gi * 2] = sv;
    *(float2*)&E12d[gi * 2] = dv;
  }
  {
    const int f = t >> 2, ic = (t & 3) * 8;
    const int4 v = *(const int4*)&ldsT[f * 40 + ic];
    *(int4*)&hbT[(size_t)(hh * 64 + f) * BN + i0 + ic] = v;
  }
}

// ============ Kernel B: mask/weight/PV(MFMA)/normalize/ELU ===================
__global__ __launch_bounds__(256, 2) void k_attn(
    const ushortT* __restrict__ hbT, const uint8_t* __restrict__ adjB,
    const float* __restrict__ E12s, const float* __restrict__ E12d,
    float* __restrict__ out) {
  __shared__ __align__(16) uint8_t smem[49664];
  __shared__ float denl[32];

  const int t    = threadIdx.x;
  const int hh   = blockIdx.x;
  const int i0   = blockIdx.y * 32;
  const int lane = t & 63;
  const int wv   = t >> 6;
  const int mt   = wv & 1;
  const int l15  = lane & 15;
  const int lq   = lane >> 4;

  ushortT* hB0 = (ushortT*)smem;
  ushortT* hB1 = hB0 + 4096;
  ushortT* wA0 = hB1 + 4096;
  ushortT* wA1 = wA0 + 2048;
  float* e12 = (float*)(wA1 + 2048);       // 4096 floats, chunk-transposed
  uint8_t* abits = (uint8_t*)(e12 + 4096); // [32][272]

  {
    const float4* g = (const float4*)(E12d + (size_t)hh * BN * 2);
#pragma unroll
    for (int rep = 0; rep < 4; ++rep) {
      const int Q = t + rep * 256;
      const int q = Q & 31;
      const int slot = (Q & ~31) + (q & 3) * 8 + (q >> 2);
      ((float4*)e12)[slot] = g[Q];
    }
    const int r = t >> 3, p = t & 7;
    const int4* ga = (const int4*)(adjB + (size_t)(i0 + r) * 256 + p * 32);
    const int4 b0 = ga[0], b1 = ga[1];
    *(int4*)(abits + r * 272 + p * 32) = b0;
    *(int4*)(abits + r * 272 + p * 32 + 16) = b1;
  }

  const int wi = t >> 3, jg = t & 7;
  const float2 ei = *(const float2*)&E12s[2 * ((size_t)hh * BN + i0 + wi)];
  const float e1i = ei.x, e2i = ei.y;
  float denp = 0.f;

  const int nt0 = (wv >> 1) * 2;
  const int arow = mt * 16 + l15;
  const int bn0 = nt0 * 16 + l15;
  f32x4 acc0 = {0.f, 0.f, 0.f, 0.f}, acc1 = {0.f, 0.f, 0.f, 0.f};

  const int S0 = t, S1 = t + 256;
  const size_t gh0 = (size_t)(hh * 64 + (S0 >> 3)) * BN + (S0 & 7) * 8;
  const size_t gh1 = (size_t)(hh * 64 + (S1 >> 3)) * BN + (S1 & 7) * 8;
  const int lo0 = (S0 >> 3) * 64 + (((S0 & 7) ^ ((S0 >> 3) & 7)) * 8);
  const int lo1 = (S1 >> 3) * 64 + (((S1 & 7) ^ ((S1 >> 3) & 7)) * 8);
  const int loW = wi * 64 + ((jg ^ (wi & 7)) * 8);

#define COMPUTE_W(cc, wbv)                                                    \
  {                                                                           \
    const uint64_t bits64 = *(const uint64_t*)(abits + wi * 272 + (cc) * 8);  \
    const unsigned bbyte = (unsigned)(bits64 >> (jg * 8)) & 0xffu;            \
    const float4* eb = ((const float4*)e12) + (cc) * 32 + jg;                 \
    const float4 r0 = eb[0];                                                  \
    const float4 r1 = eb[8];                                                  \
    const float4 r2 = eb[16];                                                 \
    const float4 r3 = eb[24];                                                 \
    float d1[8], d2[8];                                                       \
    d1[0] = r0.x; d2[0] = r0.y; d1[1] = r0.z; d2[1] = r0.w;                   \
    d1[2] = r1.x; d2[2] = r1.y; d1[3] = r1.z; d2[3] = r1.w;                   \
    d1[4] = r2.x; d2[4] = r2.y; d1[5] = r2.z; d2[5] = r2.w;                   \
    d1[6] = r3.x; d2[6] = r3.y; d1[7] = r3.z; d2[7] = r3.w;                   \
    _Pragma("unroll")                                                         \
    for (int e = 0; e < 8; ++e) {                                             \
      const float p1 = e1i * d1[e];                                           \
      const float p2 = e2i * d2[e];                                           \
      float w = fmaxf(p1, p2);                                                \
      w = ((bbyte >> e) & 1u) ? w : 0.f;                                      \
      const ushortT wu = f2bf(w);                                             \
      (wbv)[e] = (short)wu;                                                   \
      denp += bf2f(wu);                                                       \
    }                                                                         \
  }

  int4 hv0 = *(const int4*)(hbT + gh0);
  int4 hv1 = *(const int4*)(hbT + gh1);
  __syncthreads();   // e12/abits staged
  {
    short8 wb;
    COMPUTE_W(0, wb)
    *(int4*)&hB0[lo0] = hv0;
    *(int4*)&hB0[lo1] = hv1;
    *(short8*)&wA0[loW] = wb;
  }
  __syncthreads();

  for (int c = 0; c < NC; ++c) {
    const ushortT* hBc = (c & 1) ? hB1 : hB0;
    const ushortT* wAc = (c & 1) ? wA1 : wA0;
    short8 wb;
    if (c < NC - 1) {
      const size_t joff = (size_t)(c + 1) * JT;
      hv0 = *(const int4*)(hbT + gh0 + joff);
      hv1 = *(const int4*)(hbT + gh1 + joff);
      COMPUTE_W(c + 1, wb)
    }
#pragma unroll
    for (int kb = 0; kb < 2; ++kb) {
      const int ks = kb * 4 + lq;
      const short8 af  = *(const short8*)(wAc + arow * 64 + ((ks ^ (arow & 7)) * 8));
      const short8 bv0 = *(const short8*)(hBc + bn0 * 64 + ((ks ^ (bn0 & 7)) * 8));
      const short8 bv1 = *(const short8*)(hBc + (bn0 + 16) * 64 + ((ks ^ ((bn0 + 16) & 7)) * 8));
      acc0 = __builtin_amdgcn_mfma_f32_16x16x32_bf16(af, bv0, acc0, 0, 0, 0);
      acc1 = __builtin_amdgcn_mfma_f32_16x16x32_bf16(af, bv1, acc1, 0, 0, 0);
    }
    if (c < NC - 1) {
      ushortT* hBn = (c & 1) ? hB0 : hB1;
      ushortT* wAn = (c & 1) ? wA0 : wA1;
      *(int4*)&hBn[lo0] = hv0;
      *(int4*)&hBn[lo1] = hv1;
      *(short8*)&wAn[loW] = wb;
    }
    __syncthreads();
  }

  {
    float d = denp;
    d += __shfl_xor(d, 1);
    d += __shfl_xor(d, 2);
    d += __shfl_xor(d, 4);
    if ((t & 7) == 0) denl[wi] = d;
  }
  __syncthreads();

#pragma unroll
  for (int q = 0; q < 4; ++q) {
    const int row = mt * 16 + lq * 4 + q;
    const float rd = 1.f / denl[row];
    float v0 = acc0[q] * rd;
    float v1 = acc1[q] * rd;
    v0 = v0 > 0.f ? v0 : expm1f(v0);
    v1 = v1 > 0.f ? v1 : expm1f(v1);
    out[(size_t)(i0 + row) * OF + hh * 64 + nt0 * 16 + l15]       = v0;
    out[(size_t)(i0 + row) * OF + hh * 64 + (nt0 + 1) * 16 + l15] = v1;
  }
#undef COMPUTE_W
}

extern "C" void kernel_launch(void* const* d_in, const int* in_sizes, int n_in,
                              void* d_out, int out_size, void* d_ws, size_t ws_size,
                              hipStream_t stream) {
  const float* x  = (const float*)d_in[0];
  const int* adj  = (const int*)d_in[1];
  const float* Ww = (const float*)d_in[2];
  const float* Wb = (const float*)d_in[3];
  const float* a  = (const float*)d_in[4];
  float* outp = (float*)d_out;

  uint8_t* p = (uint8_t*)d_ws;
  ushortT* hbT  = (ushortT*)(p + 0x000000);   // 2 MB
  float*   E12d = (float*)  (p + 0x200000);   // 128 KB
  float*   E12s = (float*)  (p + 0x220000);   // 128 KB
  uint8_t* adjB =            p + 0x240000;    // 512 KB

  k_main<<<dim3(NH, BN / 32), 256, 0, stream>>>(x, adj, Ww, Wb, a, hbT, E12s, E12d, adjB);
  k_attn<<<dim3(NH, BN / 32), 256, 0, stream>>>(hbT, adjB, E12s, E12d, outp);
}